// Round 4
// baseline (226.161 us; speedup 1.0000x reference)
//
#include <hip/hip_runtime.h>
#include <math.h>

#define N_TOKENS    16384
#define MODEL_DIM   2048
#define NUM_EXPERTS 64
#define NK          (N_TOKENS * 2)          // 32768

// d_out layout (float32 elements)
#define OFF_TOKEN_ORDER 0
#define OFF_REVERSED    (NK)                // 32768
#define OFF_COMBINE     (2 * NK)            // 65536
#define OFF_SPLITS      (3 * NK)            // 98304
#define OFF_PROBS       (3 * NK + NUM_EXPERTS)

#define NSEG 256
#define NFRAG 16384            // 64 ksteps * 4 tiles * 64 lanes

typedef _Float16 half8 __attribute__((ext_vector_type(8)));
typedef float    f32x4 __attribute__((ext_vector_type(4)));

__device__ __forceinline__ void glds16(const void* g, void* l) {
    __builtin_amdgcn_global_load_lds(
        (const __attribute__((address_space(1))) void*)g,
        (__attribute__((address_space(3))) void*)l, 16, 0, 0);
}

// ---------------------------------------------------------------------------
// Kernel 1: pre-split W into f16 hi/lo MFMA fragments (W scaled x64 so hi is
// never f16-denormal; lo is the x4096-scaled exact residual). Also zeroes
// segHist. Fragment fr = (kstep*4 + tile)*64 + lane holds 8 f16 of
// W[tile*16 + (lane&15)][kstep*32 + (lane>>4)*8 + 0..7].
// ---------------------------------------------------------------------------
__global__ __launch_bounds__(256) void preconvert(
    const float* __restrict__ w, half8* __restrict__ WH, half8* __restrict__ WL,
    int* __restrict__ segHist)
{
    const int fr = blockIdx.x * 256 + threadIdx.x;   // 0..16383
    const int lane = fr & 63;
    const int tile = (fr >> 6) & 3;
    const int kstep = fr >> 8;
    const int e = tile * 16 + (lane & 15);
    const int kb = kstep * 32 + (lane >> 4) * 8;
    const float* src = w + (size_t)e * MODEL_DIM + kb;
    const float4 w0 = *(const float4*)(src);
    const float4 w1 = *(const float4*)(src + 4);
    const float av[8] = {w0.x, w0.y, w0.z, w0.w, w1.x, w1.y, w1.z, w1.w};
    half8 hh, hl;
#pragma unroll
    for (int j = 0; j < 8; j++) {
        const float v = av[j] * 64.0f;
        const _Float16 h = (_Float16)v;
        hh[j] = h;
        hl[j] = (_Float16)((v - (float)h) * 4096.0f);
    }
    WH[fr] = hh;
    WL[fr] = hl;
    segHist[fr] = 0;        // NSEG*NUM_EXPERTS == 16384 exactly
}

// ---------------------------------------------------------------------------
// Kernel 2: fused gate — NO barriers in the main loop, NO B staging.
// Grid 512 blocks x 256 threads (4 waves = 2 token-groups x 2 K-halves).
// Per wave per kstep (K=32):
//   - B: 8 contiguous-1KB global_load_dwordx4 straight into VGPRs (L2-hit,
//     B is 512KB and L2-resident; staging it through LDS was the round-2/3
//     wall: 256MB of duplicated LDS-direct traffic).
//   - A: 2KB staged into PRIVATE per-wave LDS via 2 coalesced glds (rows of
//     128B, 16B piece XOR-swizzled at the global address; linear LDS dest),
//     3 buffers deep, counted per-wave vmcnt(10) — no cross-wave coupling.
//   - 12 MFMA (accH, accC), fp64 fold every 8 ksteps.
// Cross-K-half fp64 reduce through separate LDS, then the verified
// softmax/top2/combine/hist epilogue. Numerics identical to rounds 1-3:
// logit = (accH + accC/4096)/64, W pre-scaled x64.
// ---------------------------------------------------------------------------
__global__ __launch_bounds__(256, 2) void gate_fused(
    const float* __restrict__ x, const half8* __restrict__ WH,
    const half8* __restrict__ WL, float* __restrict__ out,
    int* __restrict__ flat_idx, int* __restrict__ segHist)
{
    __shared__ alignas(16) unsigned char astage[4][3][2048];   // 24 KB
    __shared__ double red[128 * 17];                           // 17 KB

    const int tid  = threadIdx.x;
    const int wv   = tid >> 6;          // 0..3
    const int lane = tid & 63;
    const int kh   = wv & 1;            // K-half
    const int tg   = wv >> 1;           // token-group
    const int t0   = blockIdx.x * 32;
    const int col  = lane & 15;
    const int kg   = lane >> 4;

    // ---- A staging sources: 8 lanes per row, 16B piece XOR-swizzled ----
    const int r3 = lane >> 3;                // row within 8
    const int pp = (lane & 7) ^ r3;          // swizzled global piece
    const float* pA0 = x + (size_t)(t0 + tg * 16 + r3) * MODEL_DIM + kh * 1024 + pp * 4;
    const float* pA1 = x + (size_t)(t0 + tg * 16 + 8 + r3) * MODEL_DIM + kh * 1024 + pp * 4;
    unsigned char* mys = &astage[wv][0][0];

    // ---- A reader offsets (swizzled read: piece q at slot q^row) ----
    const int rr  = col & 7;
    const int rb  = (col >> 3) * 1024 + rr * 128;
    const int ro0 = rb + (((2 * kg)     ^ rr) << 4);
    const int ro1 = rb + (((2 * kg + 1) ^ rr) << 4);

    // ---- B pointers (contiguous 1KB per (kstep,tile) fragment) ----
    const half8* pbh = WH + ((size_t)kh * 32 * 4) * 64 + lane;
    const half8* pbl = WL + ((size_t)kh * 32 * 4) * 64 + lane;

    f32x4 accH[4], accC[4];
    double accD[4][4];
#pragma unroll
    for (int t = 0; t < 4; t++) {
        accH[t] = (f32x4){0.f, 0.f, 0.f, 0.f};
        accC[t] = (f32x4){0.f, 0.f, 0.f, 0.f};
#pragma unroll
        for (int r = 0; r < 4; r++) accD[t][r] = 0.0;
    }

    half8 bhA[4], blA[4], bhB[4], blB[4];

    // prologue: stage A kstep 0 -> buf0, kstep 1 -> buf1; load B kstep 0
    glds16(pA0, mys);
    glds16(pA1, mys + 1024);
    glds16(pA0 + 32, mys + 2048);
    glds16(pA1 + 32, mys + 2048 + 1024);
#pragma unroll
    for (int t = 0; t < 4; t++) {
        bhA[t] = pbh[t * 64];
        blA[t] = pbl[t * 64];
    }

    int j = 0, curb = 0, dstb = 2;

#define BODY(BHC, BLC, BHN, BLN) do {                                        \
    const int jn2 = (j < 30) ? (j + 2) : 31;                                 \
    glds16(pA0 + jn2 * 32, mys + dstb * 2048);                               \
    glds16(pA1 + jn2 * 32, mys + dstb * 2048 + 1024);                        \
    const half8* pbh_n = pbh + ((j < 31) ? 256 : 0);                         \
    const half8* pbl_n = pbl + ((j < 31) ? 256 : 0);                         \
    _Pragma("unroll")                                                        \
    for (int t_ = 0; t_ < 4; t_++) {                                         \
        BHN[t_] = pbh_n[t_ * 64];                                            \
        BLN[t_] = pbl_n[t_ * 64];                                            \
    }                                                                        \
    pbh = pbh_n; pbl = pbl_n;                                                \
    asm volatile("s_waitcnt vmcnt(10)" ::: "memory");                        \
    __builtin_amdgcn_sched_barrier(0);                                       \
    const float4 a0 = *(const float4*)(mys + curb * 2048 + ro0);             \
    const float4 a1 = *(const float4*)(mys + curb * 2048 + ro1);             \
    const float av_[8] = {a0.x, a0.y, a0.z, a0.w, a1.x, a1.y, a1.z, a1.w};   \
    half8 ah, al;                                                            \
    _Pragma("unroll")                                                        \
    for (int q_ = 0; q_ < 8; q_++) {                                         \
        const float v_ = av_[q_];                                            \
        const _Float16 h_ = (_Float16)v_;                                    \
        ah[q_] = h_;                                                         \
        al[q_] = (_Float16)((v_ - (float)h_) * 4096.0f);                     \
    }                                                                        \
    _Pragma("unroll")                                                        \
    for (int t_ = 0; t_ < 4; t_++) {                                         \
        accH[t_] = __builtin_amdgcn_mfma_f32_16x16x32_f16(ah, BHC[t_], accH[t_], 0, 0, 0); \
        accC[t_] = __builtin_amdgcn_mfma_f32_16x16x32_f16(ah, BLC[t_], accC[t_], 0, 0, 0); \
        accC[t_] = __builtin_amdgcn_mfma_f32_16x16x32_f16(al, BHC[t_], accC[t_], 0, 0, 0); \
    }                                                                        \
    if ((j & 7) == 7) {                                                      \
        _Pragma("unroll")                                                    \
        for (int t_ = 0; t_ < 4; t_++)                                       \
        _Pragma("unroll")                                                    \
        for (int r_ = 0; r_ < 4; r_++) {                                     \
            accD[t_][r_] += (double)accH[t_][r_] + (double)accC[t_][r_] * (1.0 / 4096.0); \
            accH[t_][r_] = 0.0f;                                             \
            accC[t_][r_] = 0.0f;                                             \
        }                                                                    \
    }                                                                        \
    curb = (curb == 2) ? 0 : curb + 1;                                       \
    dstb = (dstb == 2) ? 0 : dstb + 1;                                       \
    j++;                                                                     \
} while (0)

    for (int jj = 0; jj < 16; jj++) {
        BODY(bhA, blA, bhB, blB);
        BODY(bhB, blB, bhA, blA);
    }
#undef BODY

    // drain remaining staging, then cross-K-half fp64 reduce
    asm volatile("s_waitcnt vmcnt(0)" ::: "memory");
    __syncthreads();

    if (kh == 1) {
#pragma unroll
        for (int t = 0; t < 4; t++)
#pragma unroll
            for (int r = 0; r < 4; r++)
                red[(tg * 64 + lane) * 17 + t * 4 + r] = accD[t][r];
    }
    __syncthreads();
    if (kh == 1) return;

#pragma unroll
    for (int t = 0; t < 4; t++)
#pragma unroll
        for (int r = 0; r < 4; r++)
            accD[t][r] += red[(tg * 64 + lane) * 17 + t * 4 + r];

    // ---- epilogue: per token row, softmax + top2 + combine + hist ----
    const int rowg = lane >> 4;
#pragma unroll
    for (int r = 0; r < 4; r++) {
        float lv[4];
#pragma unroll
        for (int t = 0; t < 4; t++) lv[t] = (float)(accD[t][r] * (1.0 / 64.0));

        float m = fmaxf(fmaxf(lv[0], lv[1]), fmaxf(lv[2], lv[3]));
#pragma unroll
        for (int d = 1; d < 16; d <<= 1) m = fmaxf(m, __shfl_xor(m, d));

        // local top2 over this lane's 4 experts (ascending index)
        float l1 = -INFINITY, l2 = -INFINITY;
        int i1 = 0, i2 = 0;
#pragma unroll
        for (int t = 0; t < 4; t++) {
            const float l = lv[t];
            const int e = t * 16 + col;
            if (l > l1)      { l2 = l1; i2 = i1; l1 = l; i1 = e; }
            else if (l > l2) { l2 = l;  i2 = e; }
        }
        // cross-lane top2 merge within the 16-lane row group (lowest-idx ties)
#pragma unroll
        for (int d = 1; d < 16; d <<= 1) {
            const float ol1 = __shfl_xor(l1, d), ol2 = __shfl_xor(l2, d);
            const int   oi1 = __shfl_xor(i1, d), oi2 = __shfl_xor(i2, d);
            if (ol1 > l1 || (ol1 == l1 && oi1 < i1)) {
                if (l1 > ol2 || (l1 == ol2 && i1 < oi2)) { l2 = l1;  i2 = i1;  }
                else                                     { l2 = ol2; i2 = oi2; }
                l1 = ol1; i1 = oi1;
            } else if (ol1 > l2 || (ol1 == l2 && oi1 < i2)) {
                l2 = ol1; i2 = oi1;
            }
        }

        float ex[4];
        double sd = 0.0;
#pragma unroll
        for (int t = 0; t < 4; t++) { ex[t] = expf(lv[t] - m); sd += (double)ex[t]; }
#pragma unroll
        for (int d = 1; d < 16; d <<= 1) sd += __shfl_xor(sd, d);
        const float inv = (float)(1.0 / sd);

        const int tok = t0 + tg * 16 + rowg * 4 + r;
        float* pp2 = out + OFF_PROBS + (size_t)tok * NUM_EXPERTS + col;
#pragma unroll
        for (int t = 0; t < 4; t++) pp2[t * 16] = ex[t] * inv;

        if (col == 0) {
            const float p1 = expf(l1 - m) * inv;
            const float p2 = expf(l2 - m) * inv;
            const float e2 = expf(p2 - p1);
            const float rr2 = 1.0f / (1.0f + e2);
            out[OFF_COMBINE + 2 * tok]     = rr2;
            out[OFF_COMBINE + 2 * tok + 1] = e2 * rr2;
            flat_idx[2 * tok]     = i1;
            flat_idx[2 * tok + 1] = i2;
            atomicAdd(&segHist[(tok >> 6) * NUM_EXPERTS + i1], 1);
            atomicAdd(&segHist[(tok >> 6) * NUM_EXPERTS + i2], 1);
        }
    }
}

// ---------------------------------------------------------------------------
// Kernel 3: fused scan + scatter. 128 blocks x 256 threads; each block
// redundantly computes the full segment-offset scan in LDS (parallel across
// blocks — removes the serial 1-block scan dispatch), then does the verified
// ballot-match stable scatter for its 256 (token,slot) entries.
// ---------------------------------------------------------------------------
__global__ __launch_bounds__(256) void scan_scatter(
    const int* __restrict__ flat_idx, const int* __restrict__ segHist,
    float* __restrict__ out)
{
    __shared__ int h[NSEG * NUM_EXPERTS];   // 64 KB
    __shared__ int gtot[4 * NUM_EXPERTS];
    __shared__ int base_[NUM_EXPERTS];
    __shared__ int cnt[2 * NUM_EXPERTS];

    const int tid = threadIdx.x;
    for (int i = tid; i < NSEG * NUM_EXPERTS / 4; i += 256)
        *(int4*)(h + i * 4) = *(const int4*)(segHist + i * 4);
    if (tid < 2 * NUM_EXPERTS) cnt[tid] = 0;
    __syncthreads();

    const int e = tid & 63;
    const int g = tid >> 6;                 // 0..3
    int run = 0;
    for (int s = g * 64; s < g * 64 + 64; s++) {
        const int idx = s * NUM_EXPERTS + e;
        const int v = h[idx];
        h[idx] = run;
        run += v;
    }
    gtot[g * NUM_EXPERTS + e] = run;
    __syncthreads();

    if (tid < NUM_EXPERTS) {
        int b = 0;
#pragma unroll
        for (int gg = 0; gg < 4; gg++) {
            const int t = gtot[gg * NUM_EXPERTS + tid];
            gtot[gg * NUM_EXPERTS + tid] = b;
            b += t;
        }
        if (blockIdx.x == 0) out[OFF_SPLITS + tid] = (float)b;
        int xs = b;                          // inclusive wave scan over experts
#pragma unroll
        for (int off = 1; off < 64; off <<= 1) {
            const int v = __shfl_up(xs, off);
            if (tid >= off) xs += v;
        }
        base_[tid] = xs - b;                 // exclusive
    }
    __syncthreads();

    // ---- scatter phase ----
    const int i = blockIdx.x * 256 + tid;
    const int ee = flat_idx[i];
    const int lane = tid & 63;
    const int wv = tid >> 6;
    const int segslot = wv >> 1;
    const int seg = i >> 7;

    unsigned long long match = ~0ull;
#pragma unroll
    for (int b = 0; b < 6; b++) {
        const unsigned long long m = __ballot((ee >> b) & 1);
        match &= ((ee >> b) & 1) ? m : ~m;
    }
    const int rank = __popcll(match & ((1ull << lane) - 1ull));

    const int segoff = h[seg * NUM_EXPERTS + ee]
                     + gtot[(seg >> 6) * NUM_EXPERTS + ee] + base_[ee];

    int pos = 0;
    if ((wv & 1) == 0) {
        pos = segoff + rank;
        if (lane == __builtin_ctzll(match))
            cnt[segslot * NUM_EXPERTS + ee] = __popcll(match);
    }
    __syncthreads();
    if ((wv & 1) == 1)
        pos = segoff + cnt[segslot * NUM_EXPERTS + ee] + rank;

    out[OFF_TOKEN_ORDER + pos] = (float)(i >> 1);
    out[OFF_REVERSED + i]      = (float)pos;
}

// ---------------------------------------------------------------------------
extern "C" void kernel_launch(void* const* d_in, const int* in_sizes, int n_in,
                              void* d_out, int out_size, void* d_ws, size_t ws_size,
                              hipStream_t stream) {
    const float* x = (const float*)d_in[0];   // [16384, 2048] fp32
    const float* w = (const float*)d_in[1];   // [64, 2048] fp32
    float* out = (float*)d_out;

    int* flat_idx = (int*)d_ws;                          // NK ints
    int* segHist  = flat_idx + NK;                       // 256*64 ints
    half8* WH = (half8*)(segHist + NSEG * NUM_EXPERTS);  // 16384 frags (256 KB)
    half8* WL = WH + NFRAG;                              // 256 KB

    preconvert<<<64, 256, 0, stream>>>(w, WH, WL, segHist);
    gate_fused<<<512, 256, 0, stream>>>(x, WH, WL, out, flat_idx, segHist);
    scan_scatter<<<NK / 256, 256, 0, stream>>>(flat_idx, segHist, out);
}